// Round 2
// 420.005 us; speedup vs baseline: 1.0123x; 1.0123x over previous
//
#include <hip/hip_runtime.h>
#include <hip/hip_bf16.h>

// Problem constants
#define B_   4
#define L_   1024
#define V_   1280
#define NE_  768          // N_EMBD
#define NB_  8            // N_BIN
#define NH_  32           // N_HID
#define NO_  (NB_*NH_)    // 256 = W1 output dim
#define BL_  (B_*L_)      // 4096
#define M2_  (BL_*NB_)    // 32768 = rows of second GEMM

typedef __attribute__((ext_vector_type(8))) short bf16x8;
typedef __attribute__((ext_vector_type(4))) float floatx4;

__device__ __forceinline__ unsigned short f2bf(float f) {
    unsigned int u = __float_as_uint(f);
    u += 0x7FFFu + ((u >> 16) & 1u);      // RNE (inputs are finite, no NaN)
    return (unsigned short)(u >> 16);
}

// ---------------------------------------------------------------------------
// k0: pack h -> bf16 (row-major), W1 -> bf16 TRANSPOSED (256x768),
//     W2 -> bf16 TRANSPOSED (1280x32). Grid-stride over flat work items.
// ---------------------------------------------------------------------------
#define H4_N   (BL_*NE_/4)      // 786432 float4 conversions for h
#define W1T_N  (NO_*NE_)        // 196608
#define W2T_N  (V_*NH_)         // 40960
#define K0_TOT (H4_N + W1T_N + W2T_N)

__global__ __launch_bounds__(256) void k0_pack(const float* __restrict__ h,
                                               const float* __restrict__ W1,
                                               const float* __restrict__ W2,
                                               unsigned short* __restrict__ hb,
                                               unsigned short* __restrict__ W1T,
                                               unsigned short* __restrict__ W2T) {
    int id = blockIdx.x * 256 + threadIdx.x;
    if (id < H4_N) {
        float4 v = ((const float4*)h)[id];
        ushort4 o;
        o.x = f2bf(v.x); o.y = f2bf(v.y); o.z = f2bf(v.z); o.w = f2bf(v.w);
        ((ushort4*)hb)[id] = o;
    } else if (id < H4_N + W1T_N) {
        int j = id - H4_N;          // j = o*768 + k
        int o = j / NE_;
        int k = j - o * NE_;
        W1T[j] = f2bf(W1[(size_t)k * NO_ + o]);
    } else if (id < K0_TOT) {
        int j = id - H4_N - W1T_N;  // j = v*32 + k
        int v = j >> 5;
        int k = j & 31;
        W2T[j] = f2bf(W2[(size_t)k * V_ + v]);
    }
}

// ---------------------------------------------------------------------------
// k1: Xb[4096,256](bf16) = hb[4096,768] @ W1 (via W1T), MFMA 16x16x32 bf16.
// 64x64 tile, 256 threads (4 waves). (unchanged — ~10 us by model)
// ---------------------------------------------------------------------------
__global__ __launch_bounds__(256) void k1_gemm(const unsigned short* __restrict__ hb,
                                               const unsigned short* __restrict__ W1T,
                                               unsigned short* __restrict__ Xb) {
    __shared__ short A_lds[64][40];   // [row][k] bf16, +8 pad
    __shared__ short Bt_lds[64][40];  // [col][k] bf16, +8 pad

    const int t      = threadIdx.x;
    const int m0     = blockIdx.x * 64;
    const int n0     = blockIdx.y * 64;
    const int l      = t & 63;
    const int w      = t >> 6;
    const int lane15 = l & 15;
    const int quad   = l >> 4;

    const int srow = t >> 2;
    const int sq   = (t & 3) * 8;

    const unsigned short* aptr = hb  + (size_t)(m0 + srow) * NE_ + sq;
    const unsigned short* bptr = W1T + (size_t)(n0 + srow) * NE_ + sq;

    floatx4 acc[4];
#pragma unroll
    for (int i = 0; i < 4; ++i) acc[i] = (floatx4){0.f, 0.f, 0.f, 0.f};

    bf16x8 av = *(const bf16x8*)aptr;
    bf16x8 bv = *(const bf16x8*)bptr;

    for (int k0 = 0; k0 < NE_; k0 += 32) {
        __syncthreads();
        *(bf16x8*)&A_lds[srow][sq]  = av;
        *(bf16x8*)&Bt_lds[srow][sq] = bv;
        __syncthreads();
        if (k0 + 32 < NE_) {
            av = *(const bf16x8*)(aptr + k0 + 32);
            bv = *(const bf16x8*)(bptr + k0 + 32);
        }
        bf16x8 af = *(bf16x8*)&A_lds[w * 16 + lane15][quad * 8];
#pragma unroll
        for (int nt = 0; nt < 4; ++nt) {
            bf16x8 bf = *(bf16x8*)&Bt_lds[nt * 16 + lane15][quad * 8];
            acc[nt] = __builtin_amdgcn_mfma_f32_16x16x32_bf16(af, bf, acc[nt], 0, 0, 0);
        }
    }

    // C/D layout: col = lane&15, row = quad*4 + r   (m89/m91-verified)
    const int rbase = m0 + w * 16 + quad * 4;
#pragma unroll
    for (int nt = 0; nt < 4; ++nt)
#pragma unroll
        for (int r = 0; r < 4; ++r)
            Xb[(size_t)(rbase + r) * NO_ + n0 + nt * 16 + lane15] = f2bf(acc[nt][r]);
}

// ---------------------------------------------------------------------------
// k2: logits[32768,1280] = Xb[32768,32] @ W2 (via W2T).
// TRANSPOSED-operand MFMA: A = W2T rows (v), B = Xb rows (m).
// D[row = v-local = quad*4+r, col = m-local = lane15], so each lane's 4
// accumulator floats are 4 CONSECUTIVE v values of one output row m
// -> single global_store_dwordx4 per MFMA (was 4 scattered dwords).
// Per store instr: 16 rows x 64 B contiguous segments.
// ---------------------------------------------------------------------------
__global__ __launch_bounds__(256) void k2_logits(const unsigned short* __restrict__ Xb,
                                                 const unsigned short* __restrict__ W2T,
                                                 float* __restrict__ outL) {
    const int t      = threadIdx.x;
    const int m0     = blockIdx.x * 64;
    const int l      = t & 63;
    const int w      = t >> 6;
    const int lane15 = l & 15;
    const int quad   = l >> 4;

    const int m = m0 + w * 16 + lane15;   // output row owned by this lane (B-frag col)
    const bf16x8 bfrag = *(const bf16x8*)(Xb + (size_t)m * NH_ + quad * 8);

    float* orow = outL + (size_t)m * V_ + quad * 4;
    const unsigned short* wrow = W2T + (size_t)lane15 * NH_ + quad * 8;

#pragma unroll 4
    for (int nt = 0; nt < V_ / 16; ++nt) {
        const bf16x8 afrag = *(const bf16x8*)(wrow + (size_t)nt * 16 * NH_);
        floatx4 c = (floatx4){0.f, 0.f, 0.f, 0.f};
        c = __builtin_amdgcn_mfma_f32_16x16x32_bf16(afrag, bfrag, c, 0, 0, 0);
        *(floatx4*)(orow + nt * 16) = c;   // 16B store: v = nt*16 + quad*4 .. +3
    }
}

// ---------------------------------------------------------------------------
// k3a: suffix next-occurrence checkpoints.
// sufocc[b][y][v] = min{ i >= 32*y : targets[b][i] == v } else L.
// One backward scan of targets per (b, v) — replaces the 16.5x-redundant,
// load-imbalanced full rescans the old k3 did per i-chunk.
// ---------------------------------------------------------------------------
#define K3_S 32   // i-chunk size
#define NCH  (L_/K3_S)   // 32 chunks

__global__ __launch_bounds__(256) void k3a_scan(const int* __restrict__ targets,
                                                int* __restrict__ sufocc) {
    __shared__ int tg[L_];
    const int t = threadIdx.x;
    const int v = blockIdx.x * 256 + t;
    const int b = blockIdx.z;

    for (int j = t; j < L_; j += 256) tg[j] = targets[(size_t)b * L_ + j];
    __syncthreads();

    int cur = L_;
    for (int i = L_ - 1; i >= 0; --i) {
        if (tg[i] == v) cur = i;
        if ((i & (K3_S - 1)) == 0)
            sufocc[(size_t)(b * NCH + (i >> 5)) * V_ + v] = cur;
    }
}

// ---------------------------------------------------------------------------
// k3b: tte + censor mask. Each block scans ONLY its own 32-token chunk,
// seeded with the checkpoint for chunk y+1.
// ---------------------------------------------------------------------------
__global__ __launch_bounds__(256) void k3b_tte(const float* __restrict__ age,
                                               const float* __restrict__ tage,
                                               const int*   __restrict__ targets,
                                               const int*   __restrict__ sufocc,
                                               float* __restrict__ outT,
                                               float* __restrict__ outM) {
    __shared__ float ta[L_];
    __shared__ int   tg[K3_S];
    __shared__ float ag[K3_S];

    const int t      = threadIdx.x;
    const int v      = blockIdx.x * 256 + t;
    const int y      = blockIdx.y;
    const int istart = y * K3_S;
    const int b      = blockIdx.z;

    for (int j = t; j < L_; j += 256) ta[j] = tage[(size_t)b * L_ + j];
    if (t < K3_S) {
        tg[t] = targets[(size_t)b * L_ + istart + t];
        ag[t] = age[(size_t)b * L_ + istart + t];
    }
    __syncthreads();

    // next occurrence of v at index >= istart+32  (L if none / last chunk)
    int cur = (y == NCH - 1) ? L_
                             : sufocc[(size_t)(b * NCH + y + 1) * V_ + v];

    for (int i = K3_S - 1; i >= 0; --i) {
        const int gi = istart + i;
        if (tg[i] == v) cur = gi;

        int idx = cur;
        if (v == 0 && gi >= 1) idx = 0;   // reference's j<i scatter into v=0
        const bool noev = (idx == L_);
        const int  ic   = noev ? (L_ - 1) : idx;
        const float tte = ta[ic] - ag[i];

        outT[((size_t)(b * L_ + gi)) * V_ + v] = tte;

        const size_t mb = ((size_t)(b * L_ + gi)) * NB_ * V_ + v;
#pragma unroll
        for (int n = 0; n < NB_; ++n) {
            const float lo = n * 1.25f;
            const float hi = (n + 1) * 1.25f;
            const bool in_bin = (tte >= lo) && (tte < hi);
            outM[mb + (size_t)n * V_] = (in_bin || noev) ? 1.0f : 0.0f;
        }
    }
}

// ---------------------------------------------------------------------------
extern "C" void kernel_launch(void* const* d_in, const int* in_sizes, int n_in,
                              void* d_out, int out_size, void* d_ws, size_t ws_size,
                              hipStream_t stream) {
    const float* h       = (const float*)d_in[0];   // (4,1024,768)
    const float* age     = (const float*)d_in[1];   // (4,1024)
    const float* tage    = (const float*)d_in[2];   // (4,1024)
    /* d_in[3] = delta_t, unused by outputs */
    const int*   targets = (const int*)  d_in[4];   // (4,1024)
    const float* W1      = (const float*)d_in[5];   // (768,256)
    const float* W2      = (const float*)d_in[6];   // (32,1280)

    float* out  = (float*)d_out;
    float* outL = out;                              // 4*1024*8*1280
    float* outT = out + (size_t)BL_ * NB_ * V_;
    float* outM = outT + (size_t)BL_ * V_;

    // workspace layout (all 16B-aligned)
    char* ws = (char*)d_ws;
    unsigned short* hb  = (unsigned short*)(ws);                       // 6,291,456 B
    unsigned short* W1T = (unsigned short*)(ws + 6291456);             //   393,216 B
    unsigned short* W2T = (unsigned short*)(ws + 6291456 + 393216);    //    81,920 B
    unsigned short* Xb  = (unsigned short*)(ws + 6291456 + 393216 + 81920); // 2 MB
    int*            suf = (int*)           (ws + 6291456 + 393216 + 81920 + 2097152); // 655,360 B

    k0_pack  <<<(K0_TOT + 255) / 256, 256, 0, stream>>>(h, W1, W2, hb, W1T, W2T);
    k1_gemm  <<<dim3(BL_/64, NO_/64), 256, 0, stream>>>(hb, W1T, Xb);
    k2_logits<<<M2_/64, 256, 0, stream>>>(Xb, W2T, outL);
    k3a_scan <<<dim3(V_/256, 1, B_), 256, 0, stream>>>(targets, suf);
    k3b_tte  <<<dim3(V_/256, L_/K3_S, B_), 256, 0, stream>>>(age, tage, targets, suf, outT, outM);
}